// Round 3
// baseline (669.802 us; speedup 1.0000x reference)
//
#include <hip/hip_runtime.h>

#define KC 24
#define DC 128
#define TPB 256
#define NROWS 524288
#define CH 32              // floats per D-chunk
#define NCH 4              // DC/CH
#define RPW 64             // rows per wave
#define RPB 256            // rows per block (4 waves)
#define ZSTR 36            // stage row stride: 16B-aligned, uniform 8 words/bank

#define ACC_FLOATS (KC * DC + KC + 1)

__global__ void vq_zero_acc(float* __restrict__ acc) {
    int i = blockIdx.x * blockDim.x + threadIdx.x;
    if (i < ACC_FLOATS) acc[i] = 0.0f;
}

__global__ __launch_bounds__(TPB) void vq_main(
    const float* __restrict__ z_e, const float* __restrict__ cb,
    float* __restrict__ o_soft, float* __restrict__ o_hard,
    float* __restrict__ o_idx, float* __restrict__ o_w,
    float* __restrict__ acc)
{
    __shared__ float cb_s[KC][DC + 4];
    __shared__ float wn_s[KC];
    __shared__ float ebin[KC][DC + 4];
    __shared__ float cnt_s[KC];
    __shared__ float loss_s;
    __shared__ float zs[4][RPW * ZSTR];   // per-wave staging (36864 B)
    __shared__ int   idx_s[TPB];

    const int tid = threadIdx.x;
    const int w   = tid >> 6;
    const int l   = tid & 63;

    #pragma unroll 1
    for (int i = tid; i < KC * DC; i += TPB) cb_s[i >> 7][i & (DC - 1)] = cb[i];
    #pragma unroll 1
    for (int i = tid; i < KC * (DC + 4); i += TPB) (&ebin[0][0])[i] = 0.0f;
    if (tid < KC) cnt_s[tid] = 0.0f;
    if (tid == 0) loss_s = 0.0f;
    __syncthreads();
    if (tid < KC) {
        float s = 0.0f;
        #pragma unroll 1
        for (int d = 0; d < DC; ++d) s = fmaf(cb_s[tid][d], cb_s[tid][d], s);
        wn_s[tid] = s;
    }
    __syncthreads();

    const int rbase = blockIdx.x * RPB + w * RPW;      // wave's first row
    const float* gbase = z_e + (size_t)rbase * DC;
    float* zw = &zs[w][0];
    const int crow = l >> 3;            // cooperative row sub-index (0..7)
    const int ccol = (l & 7) * 4;       // cooperative col (0..28)

    float dot[KC];
    #pragma unroll
    for (int k = 0; k < KC; ++k) dot[k] = 0.0f;
    float zn = 0.0f;

    // ---- Pass A: coalesced load -> LDS transpose -> per-row dots ----
    float4 pre[8];
    #pragma unroll
    for (int j = 0; j < 8; ++j)
        pre[j] = *(const float4*)(gbase + (size_t)(8 * j + crow) * DC + ccol);

    #pragma unroll 1
    for (int c = 0; c < NCH; ++c) {
        #pragma unroll
        for (int j = 0; j < 8; ++j)
            *(float4*)(zw + (8 * j + crow) * ZSTR + ccol) = pre[j];
        if (c + 1 < NCH) {
            #pragma unroll
            for (int j = 0; j < 8; ++j)
                pre[j] = *(const float4*)(gbase + (size_t)(8 * j + crow) * DC
                                          + (c + 1) * CH + ccol);
        }
        float4 a[8];
        #pragma unroll
        for (int i = 0; i < 8; ++i) a[i] = *(const float4*)(zw + l * ZSTR + 4 * i);
        #pragma unroll
        for (int i = 0; i < 8; ++i)
            zn = fmaf(a[i].x, a[i].x, fmaf(a[i].y, a[i].y,
                 fmaf(a[i].z, a[i].z, fmaf(a[i].w, a[i].w, zn))));
        #pragma unroll
        for (int k = 0; k < KC; ++k) {
            #pragma unroll
            for (int i = 0; i < 8; ++i) {
                const float4 wv = *(const float4*)(&cb_s[k][c * CH + 4 * i]);
                dot[k] = fmaf(a[i].x, wv.x, fmaf(a[i].y, wv.y,
                         fmaf(a[i].z, wv.z, fmaf(a[i].w, wv.w, dot[k]))));
            }
        }
    }

    // ---- dists, argmin (first-min), softmax (same order as R2) ----
    int idx = 0;
    float best = 3.4e38f;
    #pragma unroll
    for (int k = 0; k < KC; ++k) {
        float d0 = (zn - 2.0f * dot[k]) + wn_s[k];
        dot[k] = d0;
        if (d0 < best) { best = d0; idx = k; }
    }
    float s0 = 0.0f;
    #pragma unroll
    for (int k = 0; k < KC; ++k) {
        float e0 = __expf(best - dot[k]);
        dot[k] = e0;
        s0 += e0;
    }
    const float inv0 = 1.0f / s0;
    #pragma unroll
    for (int k = 0; k < KC; ++k) dot[k] *= inv0;   // weights

    idx_s[tid] = idx;
    o_idx[rbase + l] = (float)idx;                 // coalesced (256B/wave)

    // loss = min-dist identity
    {
        float loss = best;
        #pragma unroll
        for (int off = 32; off > 0; off >>= 1) loss += __shfl_down(loss, off);
        if (l == 0) atomicAdd(&loss_s, loss);
    }

    // weights: stage own row -> cooperative coalesced store (6 x 1KB)
    #pragma unroll
    for (int q = 0; q < 6; ++q)
        *(float4*)(zw + l * ZSTR + 4 * q) =
            make_float4(dot[4*q], dot[4*q+1], dot[4*q+2], dot[4*q+3]);
    #pragma unroll
    for (int j = 0; j < 6; ++j) {
        const int off4 = j * 64 + l;          // float4 index in wave's w block
        const int off  = off4 * 4;            // float offset
        const int row  = off / 24;
        const int col  = off % 24;
        const float4 v = *(const float4*)(zw + row * ZSTR + col);
        *(float4*)(o_w + (size_t)rbase * KC + off) = v;
    }

    const int wbase = w * RPW;

    // ---- Pass B: coalesced z reload, q compute+stage, ebin, coalesced stores ----
    #pragma unroll 1
    for (int c = 0; c < NCH; ++c) {
        float4 zr[8];
        #pragma unroll
        for (int j = 0; j < 8; ++j)
            zr[j] = *(const float4*)(gbase + (size_t)(8 * j + crow) * DC
                                     + c * CH + ccol);
        // own-row soft chunk
        float4 q[8];
        #pragma unroll
        for (int i = 0; i < 8; ++i) q[i] = make_float4(0.f, 0.f, 0.f, 0.f);
        #pragma unroll
        for (int k = 0; k < KC; ++k) {
            const float wk = dot[k];
            #pragma unroll
            for (int i = 0; i < 8; ++i) {
                const float4 wv = *(const float4*)(&cb_s[k][c * CH + 4 * i]);
                q[i].x = fmaf(wk, wv.x, q[i].x);
                q[i].y = fmaf(wk, wv.y, q[i].y);
                q[i].z = fmaf(wk, wv.z, q[i].z);
                q[i].w = fmaf(wk, wv.w, q[i].w);
            }
        }
        #pragma unroll
        for (int i = 0; i < 8; ++i)
            *(float4*)(zw + l * ZSTR + 4 * i) = q[i];
        // ebin atomics from cooperative regs
        #pragma unroll
        for (int j = 0; j < 8; ++j) {
            const int id = idx_s[wbase + 8 * j + crow];
            const int d  = c * CH + ccol;
            atomicAdd(&ebin[id][d + 0], zr[j].x);
            atomicAdd(&ebin[id][d + 1], zr[j].y);
            atomicAdd(&ebin[id][d + 2], zr[j].z);
            atomicAdd(&ebin[id][d + 3], zr[j].w);
        }
        // cooperative soft store (8 lines/instr, fully covered)
        #pragma unroll
        for (int j = 0; j < 8; ++j) {
            const float4 v = *(const float4*)(zw + (8 * j + crow) * ZSTR + ccol);
            *(float4*)(o_soft + (size_t)(rbase + 8 * j + crow) * DC
                       + c * CH + ccol) = v;
        }
        // cooperative hard store straight from cb_s
        #pragma unroll
        for (int j = 0; j < 8; ++j) {
            const int id = idx_s[wbase + 8 * j + crow];
            const float4 h = *(const float4*)(&cb_s[id][c * CH + ccol]);
            *(float4*)(o_hard + (size_t)(rbase + 8 * j + crow) * DC
                       + c * CH + ccol) = h;
        }
    }
    atomicAdd(&cnt_s[idx], 1.0f);
    __syncthreads();

    #pragma unroll 1
    for (int i = tid; i < KC * DC; i += TPB)
        atomicAdd(&acc[i], ebin[i >> 7][i & (DC - 1)]);
    if (tid < KC) atomicAdd(&acc[KC * DC + tid], cnt_s[tid]);
    if (tid == 0) atomicAdd(&acc[KC * DC + KC], loss_s);
}

__global__ void vq_epilogue(
    const float* __restrict__ z_e, const float* __restrict__ ema_cs,
    const float* __restrict__ ema_es, const int* __restrict__ rand_idx,
    const float* __restrict__ acc,
    float* __restrict__ o_loss, float* __restrict__ o_cbn,
    float* __restrict__ o_ecs, float* __restrict__ o_ees)
{
    __shared__ float ecs_s[KC], sm_s[KC];
    __shared__ float n_sh;
    const int tid = threadIdx.x;
    if (tid < KC) ecs_s[tid] = 0.95f * ema_cs[tid] + 0.05f * acc[KC * DC + tid];
    __syncthreads();
    if (tid == 0) {
        float n = 0.0f;
        for (int k = 0; k < KC; ++k) n += ecs_s[k];
        n_sh = n;
    }
    __syncthreads();
    if (tid < KC) {
        float n = n_sh;
        sm_s[tid] = (ecs_s[tid] + 1e-5f) / (n + (float)KC * 1e-5f) * n;
    }
    __syncthreads();
    #pragma unroll 1
    for (int i = tid; i < KC * DC; i += TPB) {
        int k = i >> 7, d = i & (DC - 1);
        float ees = 0.95f * ema_es[i] + 0.05f * acc[i];
        float cbn = ees / sm_s[k];
        bool dead = ecs_s[k] < 0.1f;
        float rst = z_e[(size_t)rand_idx[k] * DC + d];
        o_cbn[i] = dead ? rst : cbn;
        o_ees[i] = dead ? rst : ees;
    }
    if (tid < KC) o_ecs[tid] = (ecs_s[tid] < 0.1f) ? 1.0f : ecs_s[tid];
    if (tid == 0) o_loss[0] = 1.5f * (acc[KC * DC + KC] * (1.0f / 67108864.0f));
}

extern "C" void kernel_launch(void* const* d_in, const int* in_sizes, int n_in,
                              void* d_out, int out_size, void* d_ws, size_t ws_size,
                              hipStream_t stream) {
    const float* z_e    = (const float*)d_in[0];
    const float* cb     = (const float*)d_in[1];
    const float* ema_cs = (const float*)d_in[2];
    const float* ema_es = (const float*)d_in[3];
    const int*   ridx   = (const int*)d_in[4];

    float* out = (float*)d_out;
    float* o_soft = out;                                  // 67108864
    float* o_hard = out + 67108864ll;                     // 67108864
    float* o_idx  = out + 134217728ll;                    // 524288
    float* o_w    = out + 134742016ll;                    // 12582912
    float* o_loss = out + 147324928ll;                    // 1
    float* o_cbn  = out + 147324929ll;                    // 3072
    float* o_ecs  = out + 147328001ll;                    // 24
    float* o_ees  = out + 147328025ll;                    // 3072

    float* acc = (float*)d_ws;

    vq_zero_acc<<<(ACC_FLOATS + TPB - 1) / TPB, TPB, 0, stream>>>(acc);
    vq_main<<<NROWS / RPB, TPB, 0, stream>>>(
        z_e, cb, o_soft, o_hard, o_idx, o_w, acc);
    vq_epilogue<<<1, TPB, 0, stream>>>(
        z_e, ema_cs, ema_es, ridx, acc, o_loss, o_cbn, o_ecs, o_ees);
}